// Round 2
// baseline (525.087 us; speedup 1.0000x reference)
//
#include <hip/hip_runtime.h>
#include <stdint.h>

#define HH 13
#define WW 13
#define HIN 7
#define NPOS 169   // 13*13
#define NB 33
#define NU 52
#define NE 26

// Transcribed from the reference file.
__device__ const signed char c_base[NB][2] = {
    {1,0},{3,0},{5,0},{7,0},{9,0},{11,0},
    {0,2},{2,2},{4,2},{6,2},{8,2},{10,2},{12,2},
    {1,4},{3,4},{5,4},{7,4},{9,4},{11,4},
    {2,6},{4,6},{6,6},{8,6},{10,6},
    {3,8},{5,8},{7,8},{9,8},
    {4,10},{6,10},{8,10},
    {5,12},{7,12}};

__device__ const signed char c_unev[NU][2] = {
    {5,1},{6,1},{7,1},{3,1},{0,1},{4,1},{9,1},{2,1},{10,1},{1,1},{11,1},{8,1},
    {6,3},{3,3},{7,3},{4,3},{8,3},{2,3},{9,3},{1,3},{10,3},{0,3},{11,3},{5,3},
    {6,5},{4,5},{10,5},{1,5},{9,5},{5,5},{2,5},{8,5},{7,5},{3,5},
    {4,7},{6,7},{9,7},{5,7},{8,7},{3,7},{7,7},{2,7},
    {6,9},{5,9},{7,9},{8,9},{3,9},{4,9},
    {4,11},{7,11},{5,11},{6,11}};

__device__ const signed char c_even[NE][2] = {
    {4,0},{6,0},{10,0},{2,0},{8,0},
    {5,2},{7,2},{3,2},{9,2},{1,2},{11,2},
    {2,4},{8,4},{10,4},{6,4},{4,4},
    {7,6},{9,6},{5,6},{3,6},
    {4,8},{6,8},{8,8},
    {5,10},{7,10},
    {6,12}};

// meta packing: bits[0:7)=src0, [7:14)=src1, [14:21)=src2, [21:28)=src3, [28:32)=count
__global__ __launch_bounds__(256)
void second_depool_kernel(const float* __restrict__ x,
                          float* __restrict__ out,
                          uint32_t total /* = BC*169 */) {
    __shared__ uint32_t s_meta[NPOS];
    __shared__ float    s_rdiv[NPOS];
    __shared__ short    s_map[NPOS];   // output position -> source tile index, -1 if not BASE

    const int tid = threadIdx.x;

    // ---- per-block table build (cheap, ~169 positions) ----
    for (int p = tid; p < NPOS; p += 256) {
        s_meta[p] = 0u;
        s_rdiv[p] = 1.0f;
        s_map[p]  = -1;
    }
    __syncthreads();

    if (tid < NB) {
        int bi = c_base[tid][0], bj = c_base[tid][1];
        int mc = bj >> 1;
        int mr = (bi >> 1) + ((mc + 1) & 1);   // MAP row adjustment
        int s  = mr * HIN + mc;
        int p  = bi * WW + bj;
        s_map[p]  = (short)s;
        s_meta[p] = (1u << 28) | (uint32_t)s;  // count 1, rdiv stays 1.0 (direct set)
    }
    __syncthreads();

    if (tid < NU) {
        // UNEVEN: 4 neighbors (ii,jj-1),(ii,jj+1),(ii+1,jj-1),(ii+1,jj+1), clamped.
        int ii = c_unev[tid][0], jj = c_unev[tid][1];
        int i1 = min(ii + 1, HH - 1);
        int jm = max(jj - 1, 0), jp = min(jj + 1, WW - 1);
        int q[4] = { ii * WW + jm, ii * WW + jp, i1 * WW + jm, i1 * WW + jp };
        uint32_t m = 0; int n = 0; int cnt = 0;
        #pragma unroll
        for (int k = 0; k < 4; ++k) {
            int s = s_map[q[k]];
            if (s >= 0) {                        // non-BASE neighbors contribute 0
                m |= ((uint32_t)s) << (7 * n);
                ++n;
                cnt += (x[s] != 0.0f) ? 1 : 0;   // data[0,0] nonzero-ness, from x tile 0
            }
        }
        int p = ii * WW + jj;
        s_meta[p] = m | ((uint32_t)n << 28);
        s_rdiv[p] = 1.0f / (float)max(cnt, 1);
    } else if (tid >= 64 && tid < 64 + NE) {
        int t  = tid - 64;
        int ei = c_even[t][0], ej = c_even[t][1];
        int r0 = min(ei >> 1, HIN - 1);
        int r1 = min((ei >> 1) + 1, HIN - 1);
        int c  = ej >> 1;
        int s0 = r0 * HIN + c, s1 = r1 * HIN + c;
        int cnt = ((x[s0] != 0.0f) ? 1 : 0) + ((x[s1] != 0.0f) ? 1 : 0);
        int p = ei * WW + ej;
        s_meta[p] = (2u << 28) | (uint32_t)s0 | ((uint32_t)s1 << 7);
        s_rdiv[p] = 1.0f / (float)max(cnt, 1);
    }
    __syncthreads();

    // ---- main loop: float4 over contiguous output ----
    const uint32_t nV     = total >> 2;
    const uint32_t stride = gridDim.x * blockDim.x;
    for (uint32_t v = blockIdx.x * blockDim.x + tid; v < nV; v += stride) {
        uint32_t o0 = v << 2;
        uint32_t bc = o0 / NPOS;          // compiler magic-mul (constant divisor)
        uint32_t p0 = o0 - bc * NPOS;
        const float* xb = x + (size_t)bc * 49u;
        float r[4];
        #pragma unroll
        for (int k = 0; k < 4; ++k) {
            uint32_t p = p0 + (uint32_t)k;
            const float* xx = xb;
            if (p >= NPOS) { p -= NPOS; xx += 49; }   // at most one tile crossing
            uint32_t m = s_meta[p];
            uint32_t n = m >> 28;
            float sum = 0.0f;
            if (n > 0u) sum += xx[m & 127u];
            if (n > 1u) sum += xx[(m >> 7)  & 127u];
            if (n > 2u) sum += xx[(m >> 14) & 127u];
            if (n > 3u) sum += xx[(m >> 21) & 127u];
            r[k] = sum * s_rdiv[p];
        }
        reinterpret_cast<float4*>(out)[v] = make_float4(r[0], r[1], r[2], r[3]);
    }

    // ---- scalar tail (total % 4 != 0 safety; not hit for this shape) ----
    uint32_t rem = total & 3u;
    if (rem) {
        uint32_t gid = blockIdx.x * blockDim.x + tid;
        if (gid < rem) {
            uint32_t o  = (nV << 2) + gid;
            uint32_t bc = o / NPOS;
            uint32_t p  = o - bc * NPOS;
            const float* xx = x + (size_t)bc * 49u;
            uint32_t m = s_meta[p];
            uint32_t n = m >> 28;
            float sum = 0.0f;
            if (n > 0u) sum += xx[m & 127u];
            if (n > 1u) sum += xx[(m >> 7)  & 127u];
            if (n > 2u) sum += xx[(m >> 14) & 127u];
            if (n > 3u) sum += xx[(m >> 21) & 127u];
            out[o] = sum * s_rdiv[p];
        }
    }
}

extern "C" void kernel_launch(void* const* d_in, const int* in_sizes, int n_in,
                              void* d_out, int out_size, void* d_ws, size_t ws_size,
                              hipStream_t stream) {
    (void)n_in; (void)d_ws; (void)ws_size;
    const float* x = (const float*)d_in[0];
    float* out = (float*)d_out;

    uint32_t BC    = (uint32_t)(in_sizes[0] / 49);   // B*C tiles
    uint32_t total = BC * (uint32_t)NPOS;            // == out_size
    (void)out_size;

    uint32_t nV = total >> 2;
    uint32_t blocks = (nV + 255u) / 256u;
    if (blocks > 2048u) blocks = 2048u;
    if (blocks < 1u) blocks = 1u;

    second_depool_kernel<<<dim3(blocks), dim3(256), 0, stream>>>(x, out, total);
}